// Round 9
// baseline (105.559 us; speedup 1.0000x reference)
//
#include <hip/hip_runtime.h>
#include <math.h>

#define S 512
#define NH 8
#define HD 64

typedef short short8 __attribute__((ext_vector_type(8)));
typedef float f32x4 __attribute__((ext_vector_type(4)));

__device__ __forceinline__ short bf16_hi(float x) {
  union { float f; unsigned u; } v; v.f = x;
  unsigned r = v.u + 0x7fffu + ((v.u >> 16) & 1u);
  return (short)(r >> 16);
}
__device__ __forceinline__ float bf16_val(short h) {
  union { float f; unsigned u; } v; v.u = ((unsigned)(unsigned short)h) << 16;
  return v.f;
}
__device__ __forceinline__ float softplus_f(float x) {
  return fmaxf(x, 0.f) + log1pf(__expf(-fabsf(x))) + 1e-4f;
}

// ---------------------------------------------------------------------------
// proj_gemm: z=0 -> Q = X·wq^T (3-term split-bf16, rope/softplus epilogue)
//            z=1 -> K = X·wk^T (3-term, transposed rope/softplus epilogue)
//            z=2 -> V = X·wv^T (1-term, plain fp32 epilogue)
// ---------------------------------------------------------------------------
__global__ __launch_bounds__(256) void proj_gemm(const float* __restrict__ X,
                                                 const float* __restrict__ wq,
                                                 const float* __restrict__ wk,
                                                 const float* __restrict__ wv,
                                                 const float* __restrict__ cosp,
                                                 const float* __restrict__ sinp,
                                                 float* __restrict__ qmu,
                                                 float* __restrict__ qsg,
                                                 float* __restrict__ kmuT,
                                                 float* __restrict__ ksgT,
                                                 float* __restrict__ Vbuf) {
  const int z = blockIdx.z;
  if (z == 2 && blockIdx.x >= 8) return;
  __shared__ __align__(16) char smem[52992];
  short (*Ah)[72] = (short(*)[72])(smem);
  short (*Al)[72] = (short(*)[72])(smem + 9216);
  short (*Bh)[72] = (short(*)[72])(smem + 18432);
  short (*Bl)[72] = (short(*)[72])(smem + 27648);
  float (*Cs)[69]  = (float(*)[69])(smem);            // epilogue reuse
  float (*CsC)[69] = (float(*)[69])(smem + 17664);    // cos tile (K path)
  float (*SsC)[69] = (float(*)[69])(smem + 35328);    // sin tile (K path)

  const float* Bsrc = (z == 0) ? wq : (z == 1) ? wk : wv;
  const int t = threadIdx.x;
  const int bm = blockIdx.y * 64, bn = blockIdx.x * 64;
  const int w = t >> 6, lane = t & 63;
  const int wr = (w >> 1) * 32, wc = (w & 1) * 32;
  const int fr = lane & 15, kg = (lane >> 4) << 3;
  const int r = t >> 2, c16 = (t & 3) << 4;
  f32x4 acc00 = {}, acc01 = {}, acc10 = {}, acc11 = {};

  for (int kt = 0; kt < 8; ++kt) {
    const int k0 = kt << 6;
    float4 av[4], bv[4];
#pragma unroll
    for (int i = 0; i < 4; ++i)
      av[i] = *(const float4*)(X + (size_t)(bm + r) * 512 + k0 + c16 + i * 4);
#pragma unroll
    for (int i = 0; i < 4; ++i)
      bv[i] = *(const float4*)(Bsrc + (size_t)(bn + r) * 512 + k0 + c16 + i * 4);
    __syncthreads();  // previous step's fragment reads done
#pragma unroll
    for (int i = 0; i < 4; ++i) {
      float fa[4] = {av[i].x, av[i].y, av[i].z, av[i].w};
      float fb[4] = {bv[i].x, bv[i].y, bv[i].z, bv[i].w};
      short ha[4], la[4], hb[4], lb[4];
#pragma unroll
      for (int j = 0; j < 4; ++j) {
        ha[j] = bf16_hi(fa[j]); la[j] = bf16_hi(fa[j] - bf16_val(ha[j]));
        hb[j] = bf16_hi(fb[j]); lb[j] = bf16_hi(fb[j] - bf16_val(hb[j]));
      }
      *(short4*)&Ah[r][c16 + i * 4] = make_short4(ha[0], ha[1], ha[2], ha[3]);
      *(short4*)&Bh[r][c16 + i * 4] = make_short4(hb[0], hb[1], hb[2], hb[3]);
      if (z < 2) {
        *(short4*)&Al[r][c16 + i * 4] = make_short4(la[0], la[1], la[2], la[3]);
        *(short4*)&Bl[r][c16 + i * 4] = make_short4(lb[0], lb[1], lb[2], lb[3]);
      }
    }
    __syncthreads();
#pragma unroll
    for (int ks = 0; ks < 64; ks += 32) {
      short8 ah0 = *(const short8*)&Ah[wr + fr][ks + kg];
      short8 ah1 = *(const short8*)&Ah[wr + 16 + fr][ks + kg];
      short8 bh0 = *(const short8*)&Bh[wc + fr][ks + kg];
      short8 bh1 = *(const short8*)&Bh[wc + 16 + fr][ks + kg];
      acc00 = __builtin_amdgcn_mfma_f32_16x16x32_bf16(ah0, bh0, acc00, 0, 0, 0);
      acc01 = __builtin_amdgcn_mfma_f32_16x16x32_bf16(ah0, bh1, acc01, 0, 0, 0);
      acc10 = __builtin_amdgcn_mfma_f32_16x16x32_bf16(ah1, bh0, acc10, 0, 0, 0);
      acc11 = __builtin_amdgcn_mfma_f32_16x16x32_bf16(ah1, bh1, acc11, 0, 0, 0);
      if (z < 2) {
        short8 al0 = *(const short8*)&Al[wr + fr][ks + kg];
        short8 al1 = *(const short8*)&Al[wr + 16 + fr][ks + kg];
        short8 bl0 = *(const short8*)&Bl[wc + fr][ks + kg];
        short8 bl1 = *(const short8*)&Bl[wc + 16 + fr][ks + kg];
        acc00 = __builtin_amdgcn_mfma_f32_16x16x32_bf16(al0, bh0, acc00, 0, 0, 0);
        acc01 = __builtin_amdgcn_mfma_f32_16x16x32_bf16(al0, bh1, acc01, 0, 0, 0);
        acc10 = __builtin_amdgcn_mfma_f32_16x16x32_bf16(al1, bh0, acc10, 0, 0, 0);
        acc11 = __builtin_amdgcn_mfma_f32_16x16x32_bf16(al1, bh1, acc11, 0, 0, 0);
        acc00 = __builtin_amdgcn_mfma_f32_16x16x32_bf16(ah0, bl0, acc00, 0, 0, 0);
        acc01 = __builtin_amdgcn_mfma_f32_16x16x32_bf16(ah0, bl1, acc01, 0, 0, 0);
        acc10 = __builtin_amdgcn_mfma_f32_16x16x32_bf16(ah1, bl0, acc10, 0, 0, 0);
        acc11 = __builtin_amdgcn_mfma_f32_16x16x32_bf16(ah1, bl1, acc11, 0, 0, 0);
      }
    }
  }

  const int orow = (lane >> 4) << 2;
  if (z == 2) {  // V: plain fp32 store [s][h*64+d]
#pragma unroll
    for (int j = 0; j < 4; ++j) {
      Vbuf[(size_t)(bm + wr + orow + j) * 512 + bn + wc + fr] = acc00[j];
      Vbuf[(size_t)(bm + wr + orow + j) * 512 + bn + wc + 16 + fr] = acc01[j];
      Vbuf[(size_t)(bm + wr + 16 + orow + j) * 512 + bn + wc + fr] = acc10[j];
      Vbuf[(size_t)(bm + wr + 16 + orow + j) * 512 + bn + wc + 16 + fr] = acc11[j];
    }
    return;
  }

  // ---- Q/K epilogue: stage C tile in LDS, apply rope/softplus ----
  __syncthreads();  // all fragment reads of staging LDS done
#pragma unroll
  for (int j = 0; j < 4; ++j) {
    Cs[wr + orow + j][wc + fr] = acc00[j];
    Cs[wr + orow + j][wc + 16 + fr] = acc01[j];
    Cs[wr + 16 + orow + j][wc + fr] = acc10[j];
    Cs[wr + 16 + orow + j][wc + 16 + fr] = acc11[j];
  }
  const int h = bn >> 7;
  const bool issig = (bn >> 6) & 1;
  if (z == 1 && !issig) {  // stage cos/sin tiles for transposed reads
#pragma unroll
    for (int i = 0; i < 16; ++i) {
      int rr = (i << 2) + w;
      CsC[rr][lane] = cosp[(size_t)(bm + rr) * 64 + lane];
      SsC[rr][lane] = sinp[(size_t)(bm + rr) * 64 + lane];
    }
  }
  __syncthreads();

  if (z == 0) {  // Q out: [h][q][d]
#pragma unroll
    for (int i = 0; i < 16; ++i) {
      int rr = (i << 2) + w, d = lane, s = bm + rr;
      float c = Cs[rr][d];
      if (!issig) {
        float p = Cs[rr][d ^ 32];
        float rot = (d < 32) ? -p : p;
        qmu[(size_t)((h << 9) + s) * 64 + d] =
            c * cosp[(size_t)s * 64 + d] + rot * sinp[(size_t)s * 64 + d];
      } else {
        qsg[(size_t)((h << 9) + s) * 64 + d] = softplus_f(c);
      }
    }
  } else {  // K out: transposed [h][d][s]
#pragma unroll
    for (int i = 0; i < 16; ++i) {
      int d = (i << 2) + w, sl = lane;
      float c = Cs[sl][d];
      if (!issig) {
        float p = Cs[sl][d ^ 32];
        float rot = (d < 32) ? -p : p;
        kmuT[(size_t)((h << 6) + d) * 512 + bm + sl] =
            c * CsC[sl][d] + rot * SsC[sl][d];
      } else {
        ksgT[(size_t)((h << 6) + d) * 512 + bm + sl] = softplus_f(c);
      }
    }
  }
}

// ---------- W2 scores: 16q x 64k causal tile ---------------------------------
// K staged in LDS (lgkmcnt domain). Q base addresses laundered into VGPRs via
// inline asm so Q loads compile to broadcast global_load (vmcnt domain) —
// avoids SMEM/DS lgkmcnt mixing which forces conservative full waits.
// Quad-denominator: 1 rcp per 4 d, 1 log per 8 d.
__global__ __launch_bounds__(256) void scores_kernel(const float* __restrict__ qmu,
                                                     const float* __restrict__ qsg,
                                                     const float* __restrict__ kmuT,
                                                     const float* __restrict__ ksgT,
                                                     float* __restrict__ SC) {
  const int kt = blockIdx.x, qt = blockIdx.y, h = blockIdx.z;
  const int q0 = qt * 16, k0 = kt * 64;
  if (k0 > q0 + 15) return;  // fully masked tile
  __shared__ __align__(16) float K_s[64][72];
  __shared__ __align__(16) float KS_s[64][72];
  const int t = threadIdx.x, lane = t & 63;
  {  // stage K tile transposed [d][k]
    int d = t >> 2, cb = (t & 3) * 16;
    const float* km = kmuT + (size_t)((h << 6) + d) * 512 + k0;
    const float* ks = ksgT + (size_t)((h << 6) + d) * 512 + k0;
#pragma unroll
    for (int i = 0; i < 4; ++i) {
      *(float4*)&K_s[d][cb + i * 4] = *(const float4*)(km + cb + i * 4);
      *(float4*)&KS_s[d][cb + i * 4] = *(const float4*)(ks + cb + i * 4);
    }
  }
  __syncthreads();
  const int qb = (t >> 6) << 2;  // wave's 4 q rows
  // Launder Q bases through VGPRs: forces global_load (vmcnt), not s_load.
  unsigned long long qa_ = (unsigned long long)(qmu + ((size_t)(h << 9) + q0 + qb) * 64);
  unsigned long long sa_ = (unsigned long long)(qsg + ((size_t)(h << 9) + q0 + qb) * 64);
  asm volatile("" : "+v"(qa_), "+v"(sa_));
  const float* __restrict__ qp = (const float*)qa_;
  const float* __restrict__ sp = (const float*)sa_;
  float wd[4] = {}, ld[4] = {};
  for (int d0 = 0; d0 < 64; d0 += 8) {
    float km[8], ks[8];
#pragma unroll
    for (int dd = 0; dd < 8; ++dd) {
      km[dd] = K_s[d0 + dd][lane];
      ks[dd] = KS_s[d0 + dd][lane];
    }
#pragma unroll
    for (int qi = 0; qi < 4; ++qi) {
      float4 qma = *(const float4*)(qp + qi * 64 + d0);
      float4 qmb = *(const float4*)(qp + qi * 64 + d0 + 4);
      float4 qsa = *(const float4*)(sp + qi * 64 + d0);
      float4 qsb = *(const float4*)(sp + qi * 64 + d0 + 4);
      float qm[8] = {qma.x, qma.y, qma.z, qma.w, qmb.x, qmb.y, qmb.z, qmb.w};
      float qs[8] = {qsa.x, qsa.y, qsa.z, qsa.w, qsb.x, qsb.y, qsb.z, qsb.w};
      float pp = 1.0f;
#pragma unroll
      for (int j = 0; j < 8; j += 4) {
        float s0 = qs[j] + ks[j],         s1 = qs[j + 1] + ks[j + 1];
        float s2 = qs[j + 2] + ks[j + 2], s3 = qs[j + 3] + ks[j + 3];
        float e0 = qm[j] - km[j],         e1 = qm[j + 1] - km[j + 1];
        float e2 = qm[j + 2] - km[j + 2], e3 = qm[j + 3] - km[j + 3];
        float s01 = s0 * s1, s23 = s2 * s3;
        float quad = s01 * s23;
        float n01 = fmaf(e0 * e0, s1, e1 * e1 * s0);
        float n23 = fmaf(e2 * e2, s3, e3 * e3 * s2);
        float num = fmaf(n01, s23, n23 * s01);
        wd[qi] = fmaf(num, __builtin_amdgcn_rcpf(quad), wd[qi]);
        pp = (j == 0) ? quad : pp * quad;
      }
      ld[qi] += __log2f(pp);  // s in [2e-4, ~30]: 8-product safe in fp32
    }
  }
  const int k = k0 + lane;
#pragma unroll
  for (int qi = 0; qi < 4; ++qi) {
    int q = q0 + qb + qi;
    float sc = -0.5f * (wd[qi] + 0.6931471805599453f * ld[qi]);
    if (k > q) sc = sc - 1e9f;  // exact causal mask (+ -1e9)
    SC[(size_t)((h << 9) + q) * 512 + k] = sc;
  }
}

// ---------- softmax + PV: block = (h, paired 8-row groups p and 63-p) --------
// pairing makes per-block tile work exactly 9 for every block (g0>>3+g1>>3==7)
__global__ __launch_bounds__(256) void softpv_kernel(const float* __restrict__ SC,
                                                     const float* __restrict__ Vbuf,
                                                     short* __restrict__ attn2) {
  const int p = blockIdx.x;       // 0..31
  const int h = blockIdx.y;
  const int g0 = p, g1 = 63 - p;  // 8-row groups
  const int nj0 = (g0 >> 3) + 1;  // causal k-tile count (uniform within group)
  const int nj1 = (g1 >> 3) + 1;
  const int t = threadIdx.x, w = t >> 6, lane = t & 63;
  __shared__ float p_s[16][512];  // rows 0-7: g0, rows 8-15: g1
  __shared__ __align__(16) float Vs[64][72];
  float inv0[2], inv1[2];
#pragma unroll
  for (int gi = 0; gi < 2; ++gi) {
    const int g = gi ? g1 : g0;
    const int nj = gi ? nj1 : nj0;
#pragma unroll
    for (int r = 0; r < 2; ++r) {
      const int row = w * 2 + r;
      const int q = g * 8 + row;
      float rv[8];
      float m = -3.4e38f;
#pragma unroll
      for (int j = 0; j < 8; ++j)
        if (j < nj) {
          rv[j] = SC[(size_t)((h << 9) + q) * 512 + j * 64 + lane];
          m = fmaxf(m, rv[j]);
        }
#pragma unroll
      for (int off = 32; off; off >>= 1) m = fmaxf(m, __shfl_xor(m, off));
      float sum = 0.f;
#pragma unroll
      for (int j = 0; j < 8; ++j)
        if (j < nj) {
          float pv = __expf(rv[j] - m);
          sum += pv;
          p_s[gi * 8 + row][j * 64 + lane] = pv;
        }
#pragma unroll
      for (int off = 32; off; off >>= 1) sum += __shfl_xor(sum, off);
      if (gi) inv1[r] = 1.0f / sum; else inv0[r] = 1.0f / sum;
    }
  }
  float a00 = 0.f, a01 = 0.f, a10 = 0.f, a11 = 0.f;
  for (int kt = 0; kt < nj1; ++kt) {
    __syncthreads();  // previous tile's Vs reads done (p_s rows are wave-local)
    {  // stage V tile [k][d]
      int k = t >> 2, cb = (t & 3) * 16;
      const float* vp = Vbuf + (size_t)(kt * 64 + k) * 512 + h * 64;
#pragma unroll
      for (int i = 0; i < 4; ++i)
        *(float4*)&Vs[k][cb + i * 4] = *(const float4*)(vp + cb + i * 4);
    }
    __syncthreads();
    const bool dog0 = (kt < nj0);
    const int kb = kt * 64;
    for (int k = 0; k < 64; k += 4) {
      float v0 = Vs[k + 0][lane], v1 = Vs[k + 1][lane];
      float v2 = Vs[k + 2][lane], v3 = Vs[k + 3][lane];
      float4 q10 = *(const float4*)&p_s[8 + w * 2 + 0][kb + k];
      float4 q11 = *(const float4*)&p_s[8 + w * 2 + 1][kb + k];
      a10 = fmaf(q10.x, v0, a10); a10 = fmaf(q10.y, v1, a10);
      a10 = fmaf(q10.z, v2, a10); a10 = fmaf(q10.w, v3, a10);
      a11 = fmaf(q11.x, v0, a11); a11 = fmaf(q11.y, v1, a11);
      a11 = fmaf(q11.z, v2, a11); a11 = fmaf(q11.w, v3, a11);
      if (dog0) {
        float4 q00 = *(const float4*)&p_s[w * 2 + 0][kb + k];
        float4 q01 = *(const float4*)&p_s[w * 2 + 1][kb + k];
        a00 = fmaf(q00.x, v0, a00); a00 = fmaf(q00.y, v1, a00);
        a00 = fmaf(q00.z, v2, a00); a00 = fmaf(q00.w, v3, a00);
        a01 = fmaf(q01.x, v0, a01); a01 = fmaf(q01.y, v1, a01);
        a01 = fmaf(q01.z, v2, a01); a01 = fmaf(q01.w, v3, a01);
      }
    }
  }
  {
    int qa = g0 * 8 + w * 2, qb = g1 * 8 + w * 2;
    attn2[(size_t)(qa + 0) * 512 + (h << 6) + lane] = bf16_hi(a00 * inv0[0]);
    attn2[(size_t)(qa + 1) * 512 + (h << 6) + lane] = bf16_hi(a01 * inv0[1]);
    attn2[(size_t)(qb + 0) * 512 + (h << 6) + lane] = bf16_hi(a10 * inv1[0]);
    attn2[(size_t)(qb + 1) * 512 + (h << 6) + lane] = bf16_hi(a11 * inv1[1]);
  }
}

// ---------- O projection: out = attn2(bf16) · wo^T, wo converted in staging --
__global__ __launch_bounds__(256) void gemm_o(const short* __restrict__ A2,
                                              const float* __restrict__ wo,
                                              float* __restrict__ out) {
  __shared__ __align__(16) short Ah[64][72];
  __shared__ __align__(16) short Bh[64][72];
  const int t = threadIdx.x;
  const int bm = blockIdx.y * 64, bn = blockIdx.x * 64;
  const int w = t >> 6, lane = t & 63;
  const int wr = (w >> 1) * 32, wc = (w & 1) * 32;
  const int fr = lane & 15, kg = (lane >> 4) << 3;
  const int r = t >> 2, c16 = (t & 3) << 4;
  f32x4 acc00 = {}, acc01 = {}, acc10 = {}, acc11 = {};
  for (int kt = 0; kt < 8; ++kt) {
    const int k0 = kt << 6;
    short8 a0 = *(const short8*)(A2 + (size_t)(bm + r) * 512 + k0 + c16);
    short8 a1 = *(const short8*)(A2 + (size_t)(bm + r) * 512 + k0 + c16 + 8);
    float4 bv[4];
#pragma unroll
    for (int i = 0; i < 4; ++i)
      bv[i] = *(const float4*)(wo + (size_t)(bn + r) * 512 + k0 + c16 + i * 4);
    __syncthreads();
    *(short8*)&Ah[r][c16] = a0;
    *(short8*)&Ah[r][c16 + 8] = a1;
#pragma unroll
    for (int i = 0; i < 4; ++i) {
      float fb[4] = {bv[i].x, bv[i].y, bv[i].z, bv[i].w};
      *(short4*)&Bh[r][c16 + i * 4] =
          make_short4(bf16_hi(fb[0]), bf16_hi(fb[1]), bf16_hi(fb[2]), bf16_hi(fb[3]));
    }
    __syncthreads();
#pragma unroll
    for (int ks = 0; ks < 64; ks += 32) {
      short8 af0 = *(const short8*)&Ah[wr + fr][ks + kg];
      short8 af1 = *(const short8*)&Ah[wr + 16 + fr][ks + kg];
      short8 bf0 = *(const short8*)&Bh[wc + fr][ks + kg];
      short8 bf1 = *(const short8*)&Bh[wc + 16 + fr][ks + kg];
      acc00 = __builtin_amdgcn_mfma_f32_16x16x32_bf16(af0, bf0, acc00, 0, 0, 0);
      acc01 = __builtin_amdgcn_mfma_f32_16x16x32_bf16(af0, bf1, acc01, 0, 0, 0);
      acc10 = __builtin_amdgcn_mfma_f32_16x16x32_bf16(af1, bf0, acc10, 0, 0, 0);
      acc11 = __builtin_amdgcn_mfma_f32_16x16x32_bf16(af1, bf1, acc11, 0, 0, 0);
    }
  }
  const int orow = (lane >> 4) << 2;
#pragma unroll
  for (int j = 0; j < 4; ++j) {
    out[(size_t)(bm + wr + orow + j) * 512 + bn + wc + fr] = acc00[j];
    out[(size_t)(bm + wr + orow + j) * 512 + bn + wc + 16 + fr] = acc01[j];
    out[(size_t)(bm + wr + 16 + orow + j) * 512 + bn + wc + fr] = acc10[j];
    out[(size_t)(bm + wr + 16 + orow + j) * 512 + bn + wc + 16 + fr] = acc11[j];
  }
}

// ------------------------------------------------------------------------------
extern "C" void kernel_launch(void* const* d_in, const int* in_sizes, int n_in,
                              void* d_out, int out_size, void* d_ws, size_t ws_size,
                              hipStream_t stream) {
  const float* X    = (const float*)d_in[0];
  const float* cosp = (const float*)d_in[1];
  const float* sinp = (const float*)d_in[2];
  // d_in[3] = attention_mask (recomputed inline: exact causal 0/-1e9)
  const float* wq   = (const float*)d_in[4];
  const float* wk   = (const float*)d_in[5];
  const float* wv   = (const float*)d_in[6];
  const float* wo   = (const float*)d_in[7];
  float* out = (float*)d_out;

  uint8_t* W = (uint8_t*)d_ws;
  const size_t MB = 1u << 20;
  float* qmu   = (float*)(W + 0 * MB);   // [8][512][64] 1MB
  float* qsg   = (float*)(W + 1 * MB);   // 1MB
  float* kmuT  = (float*)(W + 2 * MB);   // [8][64][512] 1MB
  float* ksgT  = (float*)(W + 3 * MB);   // 1MB
  float* Vbuf  = (float*)(W + 4 * MB);   // [512][512] 1MB
  short* attn2 = (short*)(W + 5 * MB);   // [512][512] bf16 0.5MB
  float* SC    = (float*)(W + 6 * MB);   // [8][512][512] 8MB

  proj_gemm<<<dim3(16, 8, 3), 256, 0, stream>>>(X, wq, wk, wv, cosp, sinp,
                                                qmu, qsg, kmuT, ksgT, Vbuf);
  scores_kernel<<<dim3(8, 32, 8), 256, 0, stream>>>(qmu, qsg, kmuT, ksgT, SC);
  softpv_kernel<<<dim3(32, 8), 256, 0, stream>>>(SC, Vbuf, attn2);
  gemm_o<<<dim3(8, 8), 256, 0, stream>>>(attn2, wo, out);
}

// Round 10
// 82.378 us; speedup vs baseline: 1.2814x; 1.2814x over previous
//
#include <hip/hip_runtime.h>
#include <math.h>

#define S 512
#define NH 8
#define HD 64

typedef short short8 __attribute__((ext_vector_type(8)));
typedef float f32x4 __attribute__((ext_vector_type(4)));

__device__ __forceinline__ short bf16_hi(float x) {
  union { float f; unsigned u; } v; v.f = x;
  unsigned r = v.u + 0x7fffu + ((v.u >> 16) & 1u);
  return (short)(r >> 16);
}
__device__ __forceinline__ float bf16_val(short h) {
  union { float f; unsigned u; } v; v.u = ((unsigned)(unsigned short)h) << 16;
  return v.f;
}
__device__ __forceinline__ float softplus_f(float x) {
  return fmaxf(x, 0.f) + log1pf(__expf(-fabsf(x))) + 1e-4f;
}

// ---------------------------------------------------------------------------
// proj_gemm: z=0 -> Q = X·wq^T (3-term split-bf16, rope/softplus epilogue)
//            z=1 -> K = X·wk^T (3-term, transposed rope/softplus epilogue)
//            z=2 -> V = X·wv^T (1-term, plain fp32 epilogue)
// ---------------------------------------------------------------------------
__global__ __launch_bounds__(256) void proj_gemm(const float* __restrict__ X,
                                                 const float* __restrict__ wq,
                                                 const float* __restrict__ wk,
                                                 const float* __restrict__ wv,
                                                 const float* __restrict__ cosp,
                                                 const float* __restrict__ sinp,
                                                 float* __restrict__ qmu,
                                                 float* __restrict__ qsg,
                                                 float* __restrict__ kmuT,
                                                 float* __restrict__ ksgT,
                                                 float* __restrict__ Vbuf) {
  const int z = blockIdx.z;
  if (z == 2 && blockIdx.x >= 8) return;
  __shared__ __align__(16) char smem[52992];
  short (*Ah)[72] = (short(*)[72])(smem);
  short (*Al)[72] = (short(*)[72])(smem + 9216);
  short (*Bh)[72] = (short(*)[72])(smem + 18432);
  short (*Bl)[72] = (short(*)[72])(smem + 27648);
  float (*Cs)[69]  = (float(*)[69])(smem);            // epilogue reuse
  float (*CsC)[69] = (float(*)[69])(smem + 17664);    // cos tile (K path)
  float (*SsC)[69] = (float(*)[69])(smem + 35328);    // sin tile (K path)

  const float* Bsrc = (z == 0) ? wq : (z == 1) ? wk : wv;
  const int t = threadIdx.x;
  const int bm = blockIdx.y * 64, bn = blockIdx.x * 64;
  const int w = t >> 6, lane = t & 63;
  const int wr = (w >> 1) * 32, wc = (w & 1) * 32;
  const int fr = lane & 15, kg = (lane >> 4) << 3;
  const int r = t >> 2, c16 = (t & 3) << 4;
  f32x4 acc00 = {}, acc01 = {}, acc10 = {}, acc11 = {};

  for (int kt = 0; kt < 8; ++kt) {
    const int k0 = kt << 6;
    float4 av[4], bv[4];
#pragma unroll
    for (int i = 0; i < 4; ++i)
      av[i] = *(const float4*)(X + (size_t)(bm + r) * 512 + k0 + c16 + i * 4);
#pragma unroll
    for (int i = 0; i < 4; ++i)
      bv[i] = *(const float4*)(Bsrc + (size_t)(bn + r) * 512 + k0 + c16 + i * 4);
    __syncthreads();  // previous step's fragment reads done
#pragma unroll
    for (int i = 0; i < 4; ++i) {
      float fa[4] = {av[i].x, av[i].y, av[i].z, av[i].w};
      float fb[4] = {bv[i].x, bv[i].y, bv[i].z, bv[i].w};
      short ha[4], la[4], hb[4], lb[4];
#pragma unroll
      for (int j = 0; j < 4; ++j) {
        ha[j] = bf16_hi(fa[j]); la[j] = bf16_hi(fa[j] - bf16_val(ha[j]));
        hb[j] = bf16_hi(fb[j]); lb[j] = bf16_hi(fb[j] - bf16_val(hb[j]));
      }
      *(short4*)&Ah[r][c16 + i * 4] = make_short4(ha[0], ha[1], ha[2], ha[3]);
      *(short4*)&Bh[r][c16 + i * 4] = make_short4(hb[0], hb[1], hb[2], hb[3]);
      if (z < 2) {
        *(short4*)&Al[r][c16 + i * 4] = make_short4(la[0], la[1], la[2], la[3]);
        *(short4*)&Bl[r][c16 + i * 4] = make_short4(lb[0], lb[1], lb[2], lb[3]);
      }
    }
    __syncthreads();
#pragma unroll
    for (int ks = 0; ks < 64; ks += 32) {
      short8 ah0 = *(const short8*)&Ah[wr + fr][ks + kg];
      short8 ah1 = *(const short8*)&Ah[wr + 16 + fr][ks + kg];
      short8 bh0 = *(const short8*)&Bh[wc + fr][ks + kg];
      short8 bh1 = *(const short8*)&Bh[wc + 16 + fr][ks + kg];
      acc00 = __builtin_amdgcn_mfma_f32_16x16x32_bf16(ah0, bh0, acc00, 0, 0, 0);
      acc01 = __builtin_amdgcn_mfma_f32_16x16x32_bf16(ah0, bh1, acc01, 0, 0, 0);
      acc10 = __builtin_amdgcn_mfma_f32_16x16x32_bf16(ah1, bh0, acc10, 0, 0, 0);
      acc11 = __builtin_amdgcn_mfma_f32_16x16x32_bf16(ah1, bh1, acc11, 0, 0, 0);
      if (z < 2) {
        short8 al0 = *(const short8*)&Al[wr + fr][ks + kg];
        short8 al1 = *(const short8*)&Al[wr + 16 + fr][ks + kg];
        short8 bl0 = *(const short8*)&Bl[wc + fr][ks + kg];
        short8 bl1 = *(const short8*)&Bl[wc + 16 + fr][ks + kg];
        acc00 = __builtin_amdgcn_mfma_f32_16x16x32_bf16(al0, bh0, acc00, 0, 0, 0);
        acc01 = __builtin_amdgcn_mfma_f32_16x16x32_bf16(al0, bh1, acc01, 0, 0, 0);
        acc10 = __builtin_amdgcn_mfma_f32_16x16x32_bf16(al1, bh0, acc10, 0, 0, 0);
        acc11 = __builtin_amdgcn_mfma_f32_16x16x32_bf16(al1, bh1, acc11, 0, 0, 0);
        acc00 = __builtin_amdgcn_mfma_f32_16x16x32_bf16(ah0, bl0, acc00, 0, 0, 0);
        acc01 = __builtin_amdgcn_mfma_f32_16x16x32_bf16(ah0, bl1, acc01, 0, 0, 0);
        acc10 = __builtin_amdgcn_mfma_f32_16x16x32_bf16(ah1, bl0, acc10, 0, 0, 0);
        acc11 = __builtin_amdgcn_mfma_f32_16x16x32_bf16(ah1, bl1, acc11, 0, 0, 0);
      }
    }
  }

  const int orow = (lane >> 4) << 2;
  if (z == 2) {  // V: plain fp32 store [s][h*64+d]
#pragma unroll
    for (int j = 0; j < 4; ++j) {
      Vbuf[(size_t)(bm + wr + orow + j) * 512 + bn + wc + fr] = acc00[j];
      Vbuf[(size_t)(bm + wr + orow + j) * 512 + bn + wc + 16 + fr] = acc01[j];
      Vbuf[(size_t)(bm + wr + 16 + orow + j) * 512 + bn + wc + fr] = acc10[j];
      Vbuf[(size_t)(bm + wr + 16 + orow + j) * 512 + bn + wc + 16 + fr] = acc11[j];
    }
    return;
  }

  // ---- Q/K epilogue: stage C tile in LDS, apply rope/softplus ----
  __syncthreads();  // all fragment reads of staging LDS done
#pragma unroll
  for (int j = 0; j < 4; ++j) {
    Cs[wr + orow + j][wc + fr] = acc00[j];
    Cs[wr + orow + j][wc + 16 + fr] = acc01[j];
    Cs[wr + 16 + orow + j][wc + fr] = acc10[j];
    Cs[wr + 16 + orow + j][wc + 16 + fr] = acc11[j];
  }
  const int h = bn >> 7;
  const bool issig = (bn >> 6) & 1;
  if (z == 1 && !issig) {  // stage cos/sin tiles for transposed reads
#pragma unroll
    for (int i = 0; i < 16; ++i) {
      int rr = (i << 2) + w;
      CsC[rr][lane] = cosp[(size_t)(bm + rr) * 64 + lane];
      SsC[rr][lane] = sinp[(size_t)(bm + rr) * 64 + lane];
    }
  }
  __syncthreads();

  if (z == 0) {  // Q out: [h][q][d]
#pragma unroll
    for (int i = 0; i < 16; ++i) {
      int rr = (i << 2) + w, d = lane, s = bm + rr;
      float c = Cs[rr][d];
      if (!issig) {
        float p = Cs[rr][d ^ 32];
        float rot = (d < 32) ? -p : p;
        qmu[(size_t)((h << 9) + s) * 64 + d] =
            c * cosp[(size_t)s * 64 + d] + rot * sinp[(size_t)s * 64 + d];
      } else {
        qsg[(size_t)((h << 9) + s) * 64 + d] = softplus_f(c);
      }
    }
  } else {  // K out: transposed [h][d][s]
#pragma unroll
    for (int i = 0; i < 16; ++i) {
      int d = (i << 2) + w, sl = lane;
      float c = Cs[sl][d];
      if (!issig) {
        float p = Cs[sl][d ^ 32];
        float rot = (d < 32) ? -p : p;
        kmuT[(size_t)((h << 6) + d) * 512 + bm + sl] =
            c * CsC[sl][d] + rot * SsC[sl][d];
      } else {
        ksgT[(size_t)((h << 6) + d) * 512 + bm + sl] = softplus_f(c);
      }
    }
  }
}

// ---------- W2 scores, split-D: 16q x 64k tile, 32 d's per block -------------
// half=0 -> d in [0,32) -> SCa; half=1 -> d in [32,64) -> SCb (partial, unmasked;
// softpv adds halves + applies causal mask). LDS 18.4KB -> 8 blocks/CU.
// K staged in LDS; Q via wave-uniform SMEM (proven R8 path). Quad-rcp math.
__global__ __launch_bounds__(256) void scores_kernel(const float* __restrict__ qmu,
                                                     const float* __restrict__ qsg,
                                                     const float* __restrict__ kmuT,
                                                     const float* __restrict__ ksgT,
                                                     float* __restrict__ SCa,
                                                     float* __restrict__ SCb) {
  const int kt = blockIdx.x >> 1, half = blockIdx.x & 1;
  const int qt = blockIdx.y, h = blockIdx.z;
  const int q0 = qt * 16, k0 = kt * 64;
  if (k0 > q0 + 15) return;  // fully masked tile
  float* __restrict__ SC = half ? SCb : SCa;
  const int dbase = half << 5;
  __shared__ __align__(16) float K_s[32][72];
  __shared__ __align__(16) float KS_s[32][72];
  const int t = threadIdx.x, lane = t & 63;
  {  // stage 32-row K tile transposed [d][k]
    int d = t >> 3, cb = (t & 7) * 8;
    const float* km = kmuT + (size_t)((h << 6) + dbase + d) * 512 + k0;
    const float* ks = ksgT + (size_t)((h << 6) + dbase + d) * 512 + k0;
    *(float4*)&K_s[d][cb] = *(const float4*)(km + cb);
    *(float4*)&K_s[d][cb + 4] = *(const float4*)(km + cb + 4);
    *(float4*)&KS_s[d][cb] = *(const float4*)(ks + cb);
    *(float4*)&KS_s[d][cb + 4] = *(const float4*)(ks + cb + 4);
  }
  __syncthreads();
  const int qb = __builtin_amdgcn_readfirstlane((t >> 6) << 2);  // wave's 4 q rows
  const float* __restrict__ qp = qmu + ((size_t)(h << 9) + q0 + qb) * 64 + dbase;
  const float* __restrict__ sp = qsg + ((size_t)(h << 9) + q0 + qb) * 64 + dbase;
  float wd[4] = {}, ld[4] = {};
  for (int d0 = 0; d0 < 32; d0 += 8) {
    float km[8], ks[8];
#pragma unroll
    for (int dd = 0; dd < 8; ++dd) {
      km[dd] = K_s[d0 + dd][lane];
      ks[dd] = KS_s[d0 + dd][lane];
    }
#pragma unroll
    for (int qi = 0; qi < 4; ++qi) {
      float4 qma = *(const float4*)(qp + qi * 64 + d0);
      float4 qmb = *(const float4*)(qp + qi * 64 + d0 + 4);
      float4 qsa = *(const float4*)(sp + qi * 64 + d0);
      float4 qsb = *(const float4*)(sp + qi * 64 + d0 + 4);
      float qm[8] = {qma.x, qma.y, qma.z, qma.w, qmb.x, qmb.y, qmb.z, qmb.w};
      float qs[8] = {qsa.x, qsa.y, qsa.z, qsa.w, qsb.x, qsb.y, qsb.z, qsb.w};
      float pp = 1.0f;
#pragma unroll
      for (int j = 0; j < 8; j += 4) {
        float s0 = qs[j] + ks[j],         s1 = qs[j + 1] + ks[j + 1];
        float s2 = qs[j + 2] + ks[j + 2], s3 = qs[j + 3] + ks[j + 3];
        float e0 = qm[j] - km[j],         e1 = qm[j + 1] - km[j + 1];
        float e2 = qm[j + 2] - km[j + 2], e3 = qm[j + 3] - km[j + 3];
        float s01 = s0 * s1, s23 = s2 * s3;
        float quad = s01 * s23;
        float n01 = fmaf(e0 * e0, s1, e1 * e1 * s0);
        float n23 = fmaf(e2 * e2, s3, e3 * e3 * s2);
        float num = fmaf(n01, s23, n23 * s01);
        wd[qi] = fmaf(num, __builtin_amdgcn_rcpf(quad), wd[qi]);
        pp = (j == 0) ? quad : pp * quad;
      }
      ld[qi] += __log2f(pp);  // s in [2e-4, ~30]: 8-product safe in fp32
    }
  }
  const int k = k0 + lane;
#pragma unroll
  for (int qi = 0; qi < 4; ++qi) {
    int q = q0 + qb + qi;
    SC[(size_t)((h << 9) + q) * 512 + k] =
        -0.5f * (wd[qi] + 0.6931471805599453f * ld[qi]);  // partial, unmasked
  }
}

// ---------- softmax + PV: block = (h, paired 8-row groups p and 63-p) --------
// adds the two split-D score halves and applies the causal mask inline.
__global__ __launch_bounds__(256) void softpv_kernel(const float* __restrict__ SCa,
                                                     const float* __restrict__ SCb,
                                                     const float* __restrict__ Vbuf,
                                                     short* __restrict__ attn2) {
  const int p = blockIdx.x;       // 0..31
  const int h = blockIdx.y;
  const int g0 = p, g1 = 63 - p;  // 8-row groups
  const int nj0 = (g0 >> 3) + 1;  // causal k-tile count (uniform within group)
  const int nj1 = (g1 >> 3) + 1;
  const int t = threadIdx.x, w = t >> 6, lane = t & 63;
  __shared__ float p_s[16][512];  // rows 0-7: g0, rows 8-15: g1
  __shared__ __align__(16) float Vs[64][72];
  float inv0[2], inv1[2];
#pragma unroll
  for (int gi = 0; gi < 2; ++gi) {
    const int g = gi ? g1 : g0;
    const int nj = gi ? nj1 : nj0;
#pragma unroll
    for (int r = 0; r < 2; ++r) {
      const int row = w * 2 + r;
      const int q = g * 8 + row;
      float rv[8];
      float m = -3.4e38f;
#pragma unroll
      for (int j = 0; j < 8; ++j)
        if (j < nj) {
          size_t off = (size_t)((h << 9) + q) * 512 + j * 64 + lane;
          float sc = SCa[off] + SCb[off];
          if (j * 64 + lane > q) sc = -1e9f;  // causal mask
          rv[j] = sc;
          m = fmaxf(m, sc);
        }
#pragma unroll
      for (int off = 32; off; off >>= 1) m = fmaxf(m, __shfl_xor(m, off));
      float sum = 0.f;
#pragma unroll
      for (int j = 0; j < 8; ++j)
        if (j < nj) {
          float pv = __expf(rv[j] - m);
          sum += pv;
          p_s[gi * 8 + row][j * 64 + lane] = pv;
        }
#pragma unroll
      for (int off = 32; off; off >>= 1) sum += __shfl_xor(sum, off);
      if (gi) inv1[r] = 1.0f / sum; else inv0[r] = 1.0f / sum;
    }
  }
  float a00 = 0.f, a01 = 0.f, a10 = 0.f, a11 = 0.f;
  for (int kt = 0; kt < nj1; ++kt) {
    __syncthreads();  // previous tile's Vs reads done (p_s rows are wave-local)
    {  // stage V tile [k][d]
      int k = t >> 2, cb = (t & 3) * 16;
      const float* vp = Vbuf + (size_t)(kt * 64 + k) * 512 + h * 64;
#pragma unroll
      for (int i = 0; i < 4; ++i)
        *(float4*)&Vs[k][cb + i * 4] = *(const float4*)(vp + cb + i * 4);
    }
    __syncthreads();
    const bool dog0 = (kt < nj0);
    const int kb = kt * 64;
    for (int k = 0; k < 64; k += 4) {
      float v0 = Vs[k + 0][lane], v1 = Vs[k + 1][lane];
      float v2 = Vs[k + 2][lane], v3 = Vs[k + 3][lane];
      float4 q10 = *(const float4*)&p_s[8 + w * 2 + 0][kb + k];
      float4 q11 = *(const float4*)&p_s[8 + w * 2 + 1][kb + k];
      a10 = fmaf(q10.x, v0, a10); a10 = fmaf(q10.y, v1, a10);
      a10 = fmaf(q10.z, v2, a10); a10 = fmaf(q10.w, v3, a10);
      a11 = fmaf(q11.x, v0, a11); a11 = fmaf(q11.y, v1, a11);
      a11 = fmaf(q11.z, v2, a11); a11 = fmaf(q11.w, v3, a11);
      if (dog0) {
        float4 q00 = *(const float4*)&p_s[w * 2 + 0][kb + k];
        float4 q01 = *(const float4*)&p_s[w * 2 + 1][kb + k];
        a00 = fmaf(q00.x, v0, a00); a00 = fmaf(q00.y, v1, a00);
        a00 = fmaf(q00.z, v2, a00); a00 = fmaf(q00.w, v3, a00);
        a01 = fmaf(q01.x, v0, a01); a01 = fmaf(q01.y, v1, a01);
        a01 = fmaf(q01.z, v2, a01); a01 = fmaf(q01.w, v3, a01);
      }
    }
  }
  {
    int qa = g0 * 8 + w * 2, qb = g1 * 8 + w * 2;
    attn2[(size_t)(qa + 0) * 512 + (h << 6) + lane] = bf16_hi(a00 * inv0[0]);
    attn2[(size_t)(qa + 1) * 512 + (h << 6) + lane] = bf16_hi(a01 * inv0[1]);
    attn2[(size_t)(qb + 0) * 512 + (h << 6) + lane] = bf16_hi(a10 * inv1[0]);
    attn2[(size_t)(qb + 1) * 512 + (h << 6) + lane] = bf16_hi(a11 * inv1[1]);
  }
}

// ---------- O projection: out = attn2(bf16) · wo^T, wo converted in staging --
__global__ __launch_bounds__(256) void gemm_o(const short* __restrict__ A2,
                                              const float* __restrict__ wo,
                                              float* __restrict__ out) {
  __shared__ __align__(16) short Ah[64][72];
  __shared__ __align__(16) short Bh[64][72];
  const int t = threadIdx.x;
  const int bm = blockIdx.y * 64, bn = blockIdx.x * 64;
  const int w = t >> 6, lane = t & 63;
  const int wr = (w >> 1) * 32, wc = (w & 1) * 32;
  const int fr = lane & 15, kg = (lane >> 4) << 3;
  const int r = t >> 2, c16 = (t & 3) << 4;
  f32x4 acc00 = {}, acc01 = {}, acc10 = {}, acc11 = {};
  for (int kt = 0; kt < 8; ++kt) {
    const int k0 = kt << 6;
    short8 a0 = *(const short8*)(A2 + (size_t)(bm + r) * 512 + k0 + c16);
    short8 a1 = *(const short8*)(A2 + (size_t)(bm + r) * 512 + k0 + c16 + 8);
    float4 bv[4];
#pragma unroll
    for (int i = 0; i < 4; ++i)
      bv[i] = *(const float4*)(wo + (size_t)(bn + r) * 512 + k0 + c16 + i * 4);
    __syncthreads();
    *(short8*)&Ah[r][c16] = a0;
    *(short8*)&Ah[r][c16 + 8] = a1;
#pragma unroll
    for (int i = 0; i < 4; ++i) {
      float fb[4] = {bv[i].x, bv[i].y, bv[i].z, bv[i].w};
      *(short4*)&Bh[r][c16 + i * 4] =
          make_short4(bf16_hi(fb[0]), bf16_hi(fb[1]), bf16_hi(fb[2]), bf16_hi(fb[3]));
    }
    __syncthreads();
#pragma unroll
    for (int ks = 0; ks < 64; ks += 32) {
      short8 af0 = *(const short8*)&Ah[wr + fr][ks + kg];
      short8 af1 = *(const short8*)&Ah[wr + 16 + fr][ks + kg];
      short8 bf0 = *(const short8*)&Bh[wc + fr][ks + kg];
      short8 bf1 = *(const short8*)&Bh[wc + 16 + fr][ks + kg];
      acc00 = __builtin_amdgcn_mfma_f32_16x16x32_bf16(af0, bf0, acc00, 0, 0, 0);
      acc01 = __builtin_amdgcn_mfma_f32_16x16x32_bf16(af0, bf1, acc01, 0, 0, 0);
      acc10 = __builtin_amdgcn_mfma_f32_16x16x32_bf16(af1, bf0, acc10, 0, 0, 0);
      acc11 = __builtin_amdgcn_mfma_f32_16x16x32_bf16(af1, bf1, acc11, 0, 0, 0);
    }
  }
  const int orow = (lane >> 4) << 2;
#pragma unroll
  for (int j = 0; j < 4; ++j) {
    out[(size_t)(bm + wr + orow + j) * 512 + bn + wc + fr] = acc00[j];
    out[(size_t)(bm + wr + orow + j) * 512 + bn + wc + 16 + fr] = acc01[j];
    out[(size_t)(bm + wr + 16 + orow + j) * 512 + bn + wc + fr] = acc10[j];
    out[(size_t)(bm + wr + 16 + orow + j) * 512 + bn + wc + 16 + fr] = acc11[j];
  }
}

// ------------------------------------------------------------------------------
extern "C" void kernel_launch(void* const* d_in, const int* in_sizes, int n_in,
                              void* d_out, int out_size, void* d_ws, size_t ws_size,
                              hipStream_t stream) {
  const float* X    = (const float*)d_in[0];
  const float* cosp = (const float*)d_in[1];
  const float* sinp = (const float*)d_in[2];
  // d_in[3] = attention_mask (recomputed inline: exact causal 0/-1e9)
  const float* wq   = (const float*)d_in[4];
  const float* wk   = (const float*)d_in[5];
  const float* wv   = (const float*)d_in[6];
  const float* wo   = (const float*)d_in[7];
  float* out = (float*)d_out;

  uint8_t* W = (uint8_t*)d_ws;
  const size_t MB = 1u << 20;
  float* qmu   = (float*)(W + 0 * MB);   // [8][512][64] 1MB
  float* qsg   = (float*)(W + 1 * MB);   // 1MB
  float* kmuT  = (float*)(W + 2 * MB);   // [8][64][512] 1MB
  float* ksgT  = (float*)(W + 3 * MB);   // 1MB
  float* Vbuf  = (float*)(W + 4 * MB);   // [512][512] 1MB
  short* attn2 = (short*)(W + 5 * MB);   // [512][512] bf16 0.5MB
  float* SCa   = (float*)(W + 6 * MB);   // [8][512][512] 8MB (d 0..31 partial)
  float* SCb   = (float*)(W + 14 * MB);  // [8][512][512] 8MB (d 32..63 partial)

  proj_gemm<<<dim3(16, 8, 3), 256, 0, stream>>>(X, wq, wk, wv, cosp, sinp,
                                                qmu, qsg, kmuT, ksgT, Vbuf);
  scores_kernel<<<dim3(16, 32, 8), 256, 0, stream>>>(qmu, qsg, kmuT, ksgT, SCa, SCb);
  softpv_kernel<<<dim3(32, 8), 256, 0, stream>>>(SCa, SCb, Vbuf, attn2);
  gemm_o<<<dim3(8, 8), 256, 0, stream>>>(attn2, wo, out);
}